// Round 8
// baseline (153.261 us; speedup 1.0000x reference)
//
#include <hip/hip_runtime.h>
#include <hip/hip_bf16.h>

#define B_SZ 4
#define N_SZ 512
#define IN_DIM 128
#define NH 8
#define HD 16
#define SLOPE 0.2f

#define ROWS 32
#define JT   16
#define JSEG 2
#define JB   (N_SZ / JSEG)       // 256 j's per block
#define TPB  512
#define GR_STRIDE 20             // 80 B rows: 16B-aligned, b128-friendly, 2-way bank alias (free)
#define HROW (IN_DIM + 1)

typedef float v2f __attribute__((ext_vector_type(2)));

// ws layout (floats)
#define WS_GL 0
#define WS_GR (NH * B_SZ * N_SZ * HD)                    // 262144
#define WS_OP (2 * WS_GR)                                 // 524288: [hb][seg][i][d]
#define WS_LP (WS_OP + NH * B_SZ * JSEG * N_SZ * HD)      // 1048576: [hb][seg][i]
#define WS_TOT (WS_LP + NH * B_SZ * JSEG * N_SZ)          // 1081344 floats

// ================= proj: one block per (b,i) row =================
__global__ __launch_bounds__(256) void proj_kernel(
    const float* __restrict__ hin, const float* __restrict__ Wl,
    const float* __restrict__ Wr, float* __restrict__ gl, float* __restrict__ gr)
{
    int row = blockIdx.x;            // b*N + i
    __shared__ float hrow[IN_DIM];
    int t = threadIdx.x;
    if (t < IN_DIM) hrow[t] = hin[(size_t)row * IN_DIM + t];
    __syncthreads();

    int side = t >> 7;
    int hd = t & 127;
    int head = hd >> 4, d = hd & 15;
    const float* W = (side ? Wr : Wl) + head * (IN_DIM * HD) + d;
    float acc = 0.f;
#pragma unroll 16
    for (int k = 0; k < IN_DIM; ++k)
        acc = fmaf(hrow[k], W[k * HD], acc);

    int b = row >> 9, i = row & (N_SZ - 1);
    float* g = side ? gr : gl;
    g[((size_t)(head * B_SZ + b) * N_SZ + i) * HD + d] = acc;
}

// ================= attn partial: block = (hb, itile, seg) =================
// score = 0.6*(a.gl_i) + 0.6*(a.gr_j) + 0.4 * sum_d a_d*|gl_id + gr_jd|
// no-max softmax partials over this block's 256 j's.
__global__ __launch_bounds__(TPB, 8) void attn_part_kernel(
    const float* __restrict__ gl, const float* __restrict__ gr,
    const float* __restrict__ Wak, const unsigned char* __restrict__ mask,
    float* __restrict__ opart, float* __restrict__ lpart)
{
    __shared__ float grs[JB * GR_STRIDE];   // 20480 B
    __shared__ float gls[ROWS * HD];        //  2048 B
    __shared__ float crs[JB];               //  1024 B : 0.6*(a . gr_j)

    int bid = blockIdx.x;
    int seg = bid & (JSEG - 1);
    int itile = (bid >> 1) & 15;
    int hb = bid >> 5;                 // head*4 + b
    int head = hb >> 2, b = hb & 3;
    int t = threadIdx.x;
    int j0 = seg * JB;

    // stage this segment's g_r rows (256 x 16 floats) via float4
    const float* grp = gr + ((size_t)hb * N_SZ + j0) * HD;
    for (int idx4 = t; idx4 < JB * HD / 4; idx4 += TPB) {
        float4 v = ((const float4*)grp)[idx4];
        int j = idx4 >> 2, dq = (idx4 & 3) * 4;
        float* p = &grs[j * GR_STRIDE + dq];
        *(v2f*)p = (v2f){v.x, v.y};
        *(v2f*)(p + 2) = (v2f){v.z, v.w};
    }
    // stage g_l for our 32 rows (512 elements == TPB)
    const float* glp = gl + ((size_t)hb * N_SZ + itile * ROWS) * HD;
    gls[t] = glp[t];
    __syncthreads();

    const float* ap = Wak + head * HD;   // uniform -> scalar loads

    // cr06[j] = 0.6 * (a . gr_j) for this segment's j's
    if (t < JB) {
        const float* r = &grs[t * GR_STRIDE];
        float acc = 0.f;
#pragma unroll
        for (int dd = 0; dd < HD; ++dd) acc = fmaf(ap[dd], r[dd], acc);
        crs[t] = 0.6f * acc;
    }

    int il = t >> 4;                   // 0..31
    int jt = t & 15;                   // 0..15
    int i = itile * ROWS + il;

    v2f glv[HD / 2], o[HD / 2];
    const float* grow = &gls[il * HD];
#pragma unroll
    for (int e = 0; e < HD / 2; ++e) glv[e] = *(const v2f*)(grow + 2 * e);
    float cl06;
    {
        float acc = 0.f;
#pragma unroll
        for (int dd = 0; dd < HD; ++dd) acc = fmaf(ap[dd], grow[dd], acc);
        cl06 = 0.6f * acc;
    }
#pragma unroll
    for (int e = 0; e < HD / 2; ++e) o[e] = (v2f){0.f, 0.f};

    // prefetch mask bits (16 j's per lane)
    const unsigned char* mrow = mask + ((size_t)(b * N_SZ + i)) * N_SZ + j0;
    unsigned mbits = 0;
#pragma unroll
    for (int jj = 0; jj < JB / JT; ++jj)
        mbits |= (mrow[jj * JT + jt] ? 1u : 0u) << jj;

    __syncthreads();                   // crs ready

    float l = 0.f;

#pragma unroll 4
    for (int jj = 0; jj < JB / JT; ++jj) {
        int j = jj * JT + jt;          // segment-relative
        const float* r = &grs[j * GR_STRIDE];
        float4 g01 = *(const float4*)(r);
        float4 g23 = *(const float4*)(r + 4);
        float4 g45 = *(const float4*)(r + 8);
        float4 g67 = *(const float4*)(r + 12);
        v2f gj[HD / 2] = {
            (v2f){g01.x, g01.y}, (v2f){g01.z, g01.w},
            (v2f){g23.x, g23.y}, (v2f){g23.z, g23.w},
            (v2f){g45.x, g45.y}, (v2f){g45.z, g45.w},
            (v2f){g67.x, g67.y}, (v2f){g67.z, g67.w}};

        v2f xv[HD / 2];
#pragma unroll
        for (int e = 0; e < HD / 2; ++e) xv[e] = glv[e] + gj[e];   // v_pk_add_f32

        float s0 = 0.f, s1 = 0.f;
#pragma unroll
        for (int e = 0; e < HD / 2; ++e) {              // a_d from SGPR, |x| free mod
            s0 = fmaf(ap[2 * e],     fabsf(xv[e].x), s0);
            s1 = fmaf(ap[2 * e + 1], fabsf(xv[e].y), s1);
        }
        float s = fmaf(0.4f, s0 + s1, cl06 + crs[j]);
        s = fminf(s, 80.f);
        if (mbits & (1u << jj)) s = -1e30f;

        float p = __expf(s);
        l += p;
        v2f pv = (v2f){p, p};
#pragma unroll
        for (int e = 0; e < HD / 2; ++e)
            o[e] += pv * gj[e];                          // v_pk_fma_f32
    }

    // sum-merge across the 16 jt lanes
#pragma unroll
    for (int off = 1; off < JT; off <<= 1) {
        l += __shfl_xor(l, off, 64);
#pragma unroll
        for (int e = 0; e < HD / 2; ++e) {
            v2f other;
            other.x = __shfl_xor(o[e].x, off, 64);
            other.y = __shfl_xor(o[e].y, off, 64);
            o[e] += other;
        }
    }

    if (jt == 0) {
        float res[HD];
#pragma unroll
        for (int e = 0; e < HD / 2; ++e) { res[2 * e] = o[e].x; res[2 * e + 1] = o[e].y; }
        float* op = opart + ((size_t)(hb * JSEG + seg) * N_SZ + i) * HD;
        *(float4*)op = *(float4*)res;
        *(float4*)(op + 4) = *(float4*)(res + 4);
        *(float4*)(op + 8) = *(float4*)(res + 8);
        *(float4*)(op + 12) = *(float4*)(res + 12);
        lpart[(size_t)(hb * JSEG + seg) * N_SZ + i] = l;
    }
}

// ================= combine: sum segments, normalize, relu =================
__global__ __launch_bounds__(256) void combine_kernel(
    const float* __restrict__ opart, const float* __restrict__ lpart,
    float* __restrict__ out)
{
    int gid = blockIdx.x * 256 + threadIdx.x;   // 0..262143
    int d = gid & 15;
    int r = gid >> 4;                           // hb*512 + i
    int i = r & (N_SZ - 1);
    int hb = r >> 9;
    int head = hb >> 2, b = hb & 3;

    float o = opart[((size_t)(hb * JSEG + 0) * N_SZ + i) * HD + d]
            + opart[((size_t)(hb * JSEG + 1) * N_SZ + i) * HD + d];
    float l = lpart[(size_t)(hb * JSEG + 0) * N_SZ + i]
            + lpart[(size_t)(hb * JSEG + 1) * N_SZ + i];
    out[((size_t)(b * N_SZ + i)) * (NH * HD) + head * HD + d] = fmaxf(o / l, 0.f);
}

// ================= fallback: fused kernel (no workspace) =================
__global__ __launch_bounds__(TPB) void gatv2_fused(
    const float* __restrict__ hin, const unsigned char* __restrict__ mask,
    const float* __restrict__ Wl, const float* __restrict__ Wr,
    const float* __restrict__ Wak, float* __restrict__ out)
{
    __shared__ float wrs[IN_DIM * HD];
    __shared__ float hsh[ROWS][HROW];
    __shared__ float grs[N_SZ * 18];
    __shared__ float gls[ROWS][HD];

    int bid = blockIdx.x;
    int itile = bid & 15;
    int hb = bid >> 4;
    int head = hb >> 2, b = hb & 3;
    int t = threadIdx.x;

    int jl = t >> 4;
    int d  = t & 15;

    for (int idx = t; idx < IN_DIM * HD; idx += TPB)
        wrs[idx] = Wr[head * IN_DIM * HD + idx];

    const float* hb_base = hin + (size_t)b * N_SZ * IN_DIM;
    const float* wlcol = Wl + head * IN_DIM * HD + d;

    for (int c = 0; c < N_SZ / ROWS; ++c) {
        __syncthreads();
        const float* hc = hb_base + (size_t)c * ROWS * IN_DIM;
        for (int idx = t; idx < ROWS * IN_DIM; idx += TPB)
            hsh[idx >> 7][idx & 127] = hc[idx];
        __syncthreads();

        float acc = 0.f;
#pragma unroll 16
        for (int k = 0; k < IN_DIM; ++k)
            acc = fmaf(hsh[jl][k], wrs[k * HD + d], acc);
        grs[(c * ROWS + jl) * 18 + d] = acc;

        if (c == itile) {
            float accl = 0.f;
#pragma unroll 16
            for (int k = 0; k < IN_DIM; ++k)
                accl = fmaf(hsh[jl][k], wlcol[k * HD], accl);
            gls[jl][d] = accl;
        }
    }
    __syncthreads();

    int il = jl;
    int jt = d;
    int i = itile * ROWS + il;

    float glv[HD], avv[HD];
#pragma unroll
    for (int dd = 0; dd < HD; ++dd) glv[dd] = gls[il][dd];
    const float* ap = Wak + head * HD;
#pragma unroll
    for (int dd = 0; dd < HD; ++dd) avv[dd] = ap[dd];

    const unsigned char* mrow = mask + ((size_t)(b * N_SZ + i)) * N_SZ;

    float m = -1e30f, l = 0.f;
    float o[HD];
#pragma unroll
    for (int dd = 0; dd < HD; ++dd) o[dd] = 0.f;

    for (int jj = 0; jj < N_SZ / JT; ++jj) {
        int j = jj * JT + jt;
        const float* r = &grs[j * 18];
        float gj[HD];
#pragma unroll
        for (int e = 0; e < HD / 2; ++e) {
            float2 v = *(const float2*)(r + 2 * e);
            gj[2 * e] = v.x; gj[2 * e + 1] = v.y;
        }

        float s = 0.f;
#pragma unroll
        for (int dd = 0; dd < HD; ++dd) {
            float x = glv[dd] + gj[dd];
            float lr = fmaxf(x, SLOPE * x);
            s = fmaf(avv[dd], lr, s);
        }
        if (mrow[j]) s = -1e30f;

        float mn = fmaxf(m, s);
        float cc = __expf(m - mn);
        float p = __expf(s - mn);
        l = fmaf(l, cc, p);
#pragma unroll
        for (int dd = 0; dd < HD; ++dd)
            o[dd] = fmaf(o[dd], cc, p * gj[dd]);
        m = mn;
    }

#pragma unroll
    for (int off = 1; off < JT; off <<= 1) {
        float mo = __shfl_xor(m, off, 64);
        float lo = __shfl_xor(l, off, 64);
        float mn = fmaxf(m, mo);
        float c1 = __expf(m - mn), c2 = __expf(mo - mn);
        l = l * c1 + lo * c2;
#pragma unroll
        for (int dd = 0; dd < HD; ++dd)
            o[dd] = o[dd] * c1 + __shfl_xor(o[dd], off, 64) * c2;
        m = mn;
    }

    if (jt == 0) {
        float inv = 1.f / l;
        float res[HD];
#pragma unroll
        for (int dd = 0; dd < HD; ++dd)
            res[dd] = fmaxf(o[dd] * inv, 0.f);
        float* op = out + ((size_t)(b * N_SZ + i)) * (NH * HD) + head * HD;
#pragma unroll
        for (int e = 0; e < HD / 4; ++e)
            *(float4*)(op + 4 * e) = *(float4*)(res + 4 * e);
    }
}

extern "C" void kernel_launch(void* const* d_in, const int* in_sizes, int n_in,
                              void* d_out, int out_size, void* d_ws, size_t ws_size,
                              hipStream_t stream) {
    const float* hin = (const float*)d_in[0];
    const unsigned char* mask = (const unsigned char*)d_in[1];
    const float* Wl = (const float*)d_in[2];
    const float* Wr = (const float*)d_in[3];
    const float* Wak = (const float*)d_in[4];
    float* out = (float*)d_out;
    (void)in_sizes; (void)n_in; (void)out_size;

    const size_t need = (size_t)WS_TOT * sizeof(float);   // ~4.3 MB

    if (ws_size >= need && d_ws != nullptr) {
        float* ws = (float*)d_ws;
        float* gl = ws + WS_GL;
        float* gr = ws + WS_GR;
        float* op = ws + WS_OP;
        float* lp = ws + WS_LP;
        proj_kernel<<<B_SZ * N_SZ, 256, 0, stream>>>(hin, Wl, Wr, gl, gr);
        attn_part_kernel<<<NH * B_SZ * 16 * JSEG, TPB, 0, stream>>>(
            gl, gr, Wak, mask, op, lp);
        combine_kernel<<<(NH * B_SZ * N_SZ * HD) / 256, 256, 0, stream>>>(
            op, lp, out);
    } else {
        gatv2_fused<<<NH * B_SZ * (N_SZ / ROWS), TPB, 0, stream>>>(
            hin, mask, Wl, Wr, Wak, out);
    }
}

// Round 9
// 95.185 us; speedup vs baseline: 1.6101x; 1.6101x over previous
//
#include <hip/hip_runtime.h>
#include <hip/hip_bf16.h>

#define B_SZ 4
#define N_SZ 512
#define IN_DIM 128
#define NH 8
#define HD 16
#define SLOPE 0.2f

#define ROWS 32
#define JT   16
#define JSEG 2
#define JB   (N_SZ / JSEG)       // 256 j's per block
#define TPB  512
#define GR_STRIDE 20             // 80 B rows: 16B-aligned, b128 loads, 2-way alias free
#define HROW (IN_DIM + 1)

typedef float v2f __attribute__((ext_vector_type(2)));

// ws layout (floats)
#define WS_GL 0
#define WS_GR (NH * B_SZ * N_SZ * HD)                    // 262144
#define WS_OP (2 * WS_GR)                                 // 524288: [hb][seg][i][d]
#define WS_LP (WS_OP + NH * B_SZ * JSEG * N_SZ * HD)      // [hb][seg][i]
#define WS_TOT (WS_LP + NH * B_SZ * JSEG * N_SZ)

// ================= proj: one block per (b,i) row =================
__global__ __launch_bounds__(256) void proj_kernel(
    const float* __restrict__ hin, const float* __restrict__ Wl,
    const float* __restrict__ Wr, float* __restrict__ gl, float* __restrict__ gr)
{
    int row = blockIdx.x;            // b*N + i
    __shared__ float hrow[IN_DIM];
    int t = threadIdx.x;
    if (t < IN_DIM) hrow[t] = hin[(size_t)row * IN_DIM + t];
    __syncthreads();

    int side = t >> 7;
    int hd = t & 127;
    int head = hd >> 4, d = hd & 15;
    const float* W = (side ? Wr : Wl) + head * (IN_DIM * HD) + d;
    float acc = 0.f;
#pragma unroll 16
    for (int k = 0; k < IN_DIM; ++k)
        acc = fmaf(hrow[k], W[k * HD], acc);

    int b = row >> 9, i = row & (N_SZ - 1);
    float* g = side ? gr : gl;
    g[((size_t)(head * B_SZ + b) * N_SZ + i) * HD + d] = acc;
}

// ================= attn partial: block = (hb, itile, seg) =================
// score = 0.6*(a.gl_i) + 0.6*(a.gr_j) + 0.4 * sum_d a_d*|gl_id + gr_jd|
// no-max softmax partials over this block's 256 j's.
// NOTE: __launch_bounds__(512,4) -> 128-VGPR cap (52 used, NO spill).
// (512,8) in round 8 forced a 64-VGPR cap -> scratch spill -> 190 MB/dispatch HBM.
__global__ __launch_bounds__(TPB, 4) void attn_part_kernel(
    const float* __restrict__ gl, const float* __restrict__ gr,
    const float* __restrict__ Wak, const unsigned char* __restrict__ mask,
    float* __restrict__ opart, float* __restrict__ lpart)
{
    __shared__ float grs[JB * GR_STRIDE];   // 20480 B
    __shared__ float gls[ROWS * HD];        //  2048 B
    __shared__ float crs[JB];               //  1024 B : 0.6*(a . gr_j)

    int bid = blockIdx.x;
    int seg = bid & (JSEG - 1);
    int itile = (bid >> 1) & 15;
    int hb = bid >> 5;                 // head*4 + b
    int head = hb >> 2, b = hb & 3;
    int t = threadIdx.x;
    int j0 = seg * JB;

    // stage this segment's g_r rows (256 x 16 floats) via float4
    const float* grp = gr + ((size_t)hb * N_SZ + j0) * HD;
    for (int idx4 = t; idx4 < JB * HD / 4; idx4 += TPB) {
        float4 v = ((const float4*)grp)[idx4];
        int j = idx4 >> 2, dq = (idx4 & 3) * 4;
        float* p = &grs[j * GR_STRIDE + dq];
        *(v2f*)p = (v2f){v.x, v.y};
        *(v2f*)(p + 2) = (v2f){v.z, v.w};
    }
    // stage g_l for our 32 rows (512 elements == TPB)
    const float* glp = gl + ((size_t)hb * N_SZ + itile * ROWS) * HD;
    gls[t] = glp[t];
    __syncthreads();

    const float* ap = Wak + head * HD;   // uniform -> scalar loads

    // cr06[j] = 0.6 * (a . gr_j) for this segment's j's
    if (t < JB) {
        const float* r = &grs[t * GR_STRIDE];
        float acc = 0.f;
#pragma unroll
        for (int dd = 0; dd < HD; ++dd) acc = fmaf(ap[dd], r[dd], acc);
        crs[t] = 0.6f * acc;
    }

    int il = t >> 4;                   // 0..31
    int jt = t & 15;                   // 0..15
    int i = itile * ROWS + il;

    v2f glv[HD / 2], o[HD / 2];
    const float* grow = &gls[il * HD];
#pragma unroll
    for (int e = 0; e < HD / 2; ++e) glv[e] = *(const v2f*)(grow + 2 * e);
    float cl06;
    {
        float acc = 0.f;
#pragma unroll
        for (int dd = 0; dd < HD; ++dd) acc = fmaf(ap[dd], grow[dd], acc);
        cl06 = 0.6f * acc;
    }
#pragma unroll
    for (int e = 0; e < HD / 2; ++e) o[e] = (v2f){0.f, 0.f};

    // prefetch mask bits (16 j's per lane)
    const unsigned char* mrow = mask + ((size_t)(b * N_SZ + i)) * N_SZ + j0;
    unsigned mbits = 0;
#pragma unroll
    for (int jj = 0; jj < JB / JT; ++jj)
        mbits |= (mrow[jj * JT + jt] ? 1u : 0u) << jj;

    __syncthreads();                   // crs ready

    float l = 0.f;

#pragma unroll 2
    for (int jj = 0; jj < JB / JT; ++jj) {
        int j = jj * JT + jt;          // segment-relative
        const float* r = &grs[j * GR_STRIDE];
        float4 g01 = *(const float4*)(r);
        float4 g23 = *(const float4*)(r + 4);
        float4 g45 = *(const float4*)(r + 8);
        float4 g67 = *(const float4*)(r + 12);
        v2f gj[HD / 2] = {
            (v2f){g01.x, g01.y}, (v2f){g01.z, g01.w},
            (v2f){g23.x, g23.y}, (v2f){g23.z, g23.w},
            (v2f){g45.x, g45.y}, (v2f){g45.z, g45.w},
            (v2f){g67.x, g67.y}, (v2f){g67.z, g67.w}};

        float s0 = 0.f, s1 = 0.f;
#pragma unroll
        for (int e = 0; e < HD / 2; ++e) {       // pk_add + 2 fma (|x| is free mod)
            v2f x = glv[e] + gj[e];
            s0 = fmaf(ap[2 * e],     fabsf(x.x), s0);
            s1 = fmaf(ap[2 * e + 1], fabsf(x.y), s1);
        }
        float s = fmaf(0.4f, s0 + s1, cl06 + crs[j]);
        s = fminf(s, 80.f);
        if (mbits & (1u << jj)) s = -1e30f;

        float p = __expf(s);
        l += p;
        v2f pv = (v2f){p, p};
#pragma unroll
        for (int e = 0; e < HD / 2; ++e)
            o[e] += pv * gj[e];                   // v_pk_fma_f32
    }

    // sum-merge across the 16 jt lanes
#pragma unroll
    for (int off = 1; off < JT; off <<= 1) {
        l += __shfl_xor(l, off, 64);
#pragma unroll
        for (int e = 0; e < HD / 2; ++e) {
            v2f other;
            other.x = __shfl_xor(o[e].x, off, 64);
            other.y = __shfl_xor(o[e].y, off, 64);
            o[e] += other;
        }
    }

    if (jt == 0) {
        float res[HD];
#pragma unroll
        for (int e = 0; e < HD / 2; ++e) { res[2 * e] = o[e].x; res[2 * e + 1] = o[e].y; }
        float* op = opart + ((size_t)(hb * JSEG + seg) * N_SZ + i) * HD;
        *(float4*)op = *(float4*)res;
        *(float4*)(op + 4) = *(float4*)(res + 4);
        *(float4*)(op + 8) = *(float4*)(res + 8);
        *(float4*)(op + 12) = *(float4*)(res + 12);
        lpart[(size_t)(hb * JSEG + seg) * N_SZ + i] = l;
    }
}

// ================= combine: sum segments, normalize, relu =================
__global__ __launch_bounds__(256) void combine_kernel(
    const float* __restrict__ opart, const float* __restrict__ lpart,
    float* __restrict__ out)
{
    int gid = blockIdx.x * 256 + threadIdx.x;   // 0..262143
    int d = gid & 15;
    int r = gid >> 4;                           // hb*512 + i
    int i = r & (N_SZ - 1);
    int hb = r >> 9;
    int head = hb >> 2, b = hb & 3;

    float o = opart[((size_t)(hb * JSEG + 0) * N_SZ + i) * HD + d]
            + opart[((size_t)(hb * JSEG + 1) * N_SZ + i) * HD + d];
    float l = lpart[(size_t)(hb * JSEG + 0) * N_SZ + i]
            + lpart[(size_t)(hb * JSEG + 1) * N_SZ + i];
    out[((size_t)(b * N_SZ + i)) * (NH * HD) + head * HD + d] = fmaxf(o / l, 0.f);
}

// ================= fallback: fused kernel (no workspace) =================
__global__ __launch_bounds__(TPB) void gatv2_fused(
    const float* __restrict__ hin, const unsigned char* __restrict__ mask,
    const float* __restrict__ Wl, const float* __restrict__ Wr,
    const float* __restrict__ Wak, float* __restrict__ out)
{
    __shared__ float wrs[IN_DIM * HD];
    __shared__ float hsh[ROWS][HROW];
    __shared__ float grs[N_SZ * 18];
    __shared__ float gls[ROWS][HD];

    int bid = blockIdx.x;
    int itile = bid & 15;
    int hb = bid >> 4;
    int head = hb >> 2, b = hb & 3;
    int t = threadIdx.x;

    int jl = t >> 4;
    int d  = t & 15;

    for (int idx = t; idx < IN_DIM * HD; idx += TPB)
        wrs[idx] = Wr[head * IN_DIM * HD + idx];

    const float* hb_base = hin + (size_t)b * N_SZ * IN_DIM;
    const float* wlcol = Wl + head * IN_DIM * HD + d;

    for (int c = 0; c < N_SZ / ROWS; ++c) {
        __syncthreads();
        const float* hc = hb_base + (size_t)c * ROWS * IN_DIM;
        for (int idx = t; idx < ROWS * IN_DIM; idx += TPB)
            hsh[idx >> 7][idx & 127] = hc[idx];
        __syncthreads();

        float acc = 0.f;
#pragma unroll 16
        for (int k = 0; k < IN_DIM; ++k)
            acc = fmaf(hsh[jl][k], wrs[k * HD + d], acc);
        grs[(c * ROWS + jl) * 18 + d] = acc;

        if (c == itile) {
            float accl = 0.f;
#pragma unroll 16
            for (int k = 0; k < IN_DIM; ++k)
                accl = fmaf(hsh[jl][k], wlcol[k * HD], accl);
            gls[jl][d] = accl;
        }
    }
    __syncthreads();

    int il = jl;
    int jt = d;
    int i = itile * ROWS + il;

    float glv[HD], avv[HD];
#pragma unroll
    for (int dd = 0; dd < HD; ++dd) glv[dd] = gls[il][dd];
    const float* ap = Wak + head * HD;
#pragma unroll
    for (int dd = 0; dd < HD; ++dd) avv[dd] = ap[dd];

    const unsigned char* mrow = mask + ((size_t)(b * N_SZ + i)) * N_SZ;

    float m = -1e30f, l = 0.f;
    float o[HD];
#pragma unroll
    for (int dd = 0; dd < HD; ++dd) o[dd] = 0.f;

    for (int jj = 0; jj < N_SZ / JT; ++jj) {
        int j = jj * JT + jt;
        const float* r = &grs[j * 18];
        float gj[HD];
#pragma unroll
        for (int e = 0; e < HD / 2; ++e) {
            float2 v = *(const float2*)(r + 2 * e);
            gj[2 * e] = v.x; gj[2 * e + 1] = v.y;
        }

        float s = 0.f;
#pragma unroll
        for (int dd = 0; dd < HD; ++dd) {
            float x = glv[dd] + gj[dd];
            float lr = fmaxf(x, SLOPE * x);
            s = fmaf(avv[dd], lr, s);
        }
        if (mrow[j]) s = -1e30f;

        float mn = fmaxf(m, s);
        float cc = __expf(m - mn);
        float p = __expf(s - mn);
        l = fmaf(l, cc, p);
#pragma unroll
        for (int dd = 0; dd < HD; ++dd)
            o[dd] = fmaf(o[dd], cc, p * gj[dd]);
        m = mn;
    }

#pragma unroll
    for (int off = 1; off < JT; off <<= 1) {
        float mo = __shfl_xor(m, off, 64);
        float lo = __shfl_xor(l, off, 64);
        float mn = fmaxf(m, mo);
        float c1 = __expf(m - mn), c2 = __expf(mo - mn);
        l = l * c1 + lo * c2;
#pragma unroll
        for (int dd = 0; dd < HD; ++dd)
            o[dd] = o[dd] * c1 + __shfl_xor(o[dd], off, 64) * c2;
        m = mn;
    }

    if (jt == 0) {
        float inv = 1.f / l;
        float res[HD];
#pragma unroll
        for (int dd = 0; dd < HD; ++dd)
            res[dd] = fmaxf(o[dd] * inv, 0.f);
        float* op = out + ((size_t)(b * N_SZ + i)) * (NH * HD) + head * HD;
#pragma unroll
        for (int e = 0; e < HD / 4; ++e)
            *(float4*)(op + 4 * e) = *(float4*)(res + 4 * e);
    }
}

extern "C" void kernel_launch(void* const* d_in, const int* in_sizes, int n_in,
                              void* d_out, int out_size, void* d_ws, size_t ws_size,
                              hipStream_t stream) {
    const float* hin = (const float*)d_in[0];
    const unsigned char* mask = (const unsigned char*)d_in[1];
    const float* Wl = (const float*)d_in[2];
    const float* Wr = (const float*)d_in[3];
    const float* Wak = (const float*)d_in[4];
    float* out = (float*)d_out;
    (void)in_sizes; (void)n_in; (void)out_size;

    const size_t need = (size_t)WS_TOT * sizeof(float);   // ~4.3 MB

    if (ws_size >= need && d_ws != nullptr) {
        float* ws = (float*)d_ws;
        float* gl = ws + WS_GL;
        float* gr = ws + WS_GR;
        float* op = ws + WS_OP;
        float* lp = ws + WS_LP;
        proj_kernel<<<B_SZ * N_SZ, 256, 0, stream>>>(hin, Wl, Wr, gl, gr);
        attn_part_kernel<<<NH * B_SZ * 16 * JSEG, TPB, 0, stream>>>(
            gl, gr, Wak, mask, op, lp);
        combine_kernel<<<(NH * B_SZ * N_SZ * HD) / 256, 256, 0, stream>>>(
            op, lp, out);
    } else {
        gatv2_fused<<<NH * B_SZ * (N_SZ / ROWS), TPB, 0, stream>>>(
            hin, mask, Wl, Wr, Wak, out);
    }
}

// Round 10
// 94.893 us; speedup vs baseline: 1.6151x; 1.0031x over previous
//
#include <hip/hip_runtime.h>
#include <hip/hip_bf16.h>

#define B_SZ 4
#define N_SZ 512
#define IN_DIM 128
#define NH 8
#define HD 16
#define SLOPE 0.2f

#define ROWS 64                  // i-rows per attn block
#define JT   8                   // j-lanes per i-row
#define JSEG 2
#define JB   (N_SZ / JSEG)       // 256 j's per block
#define TPB  512
#define GR_STRIDE 20             // 80 B rows: 16B-aligned, b128, banks 20j%32 distinct for 8 lanes
#define GLS_STRIDE 20

typedef float v2f __attribute__((ext_vector_type(2)));

// ws layout (floats)
#define WS_GL 0
#define WS_GR (NH * B_SZ * N_SZ * HD)                    // 262144
#define WS_OP (2 * WS_GR)                                 // [hb][seg][i][d]
#define WS_LP (WS_OP + NH * B_SZ * JSEG * N_SZ * HD)      // [hb][seg][i]
#define WS_TOT (WS_LP + NH * B_SZ * JSEG * N_SZ)

// ================= proj: one block per (b,i) row =================
__global__ __launch_bounds__(256) void proj_kernel(
    const float* __restrict__ hin, const float* __restrict__ Wl,
    const float* __restrict__ Wr, float* __restrict__ gl, float* __restrict__ gr)
{
    int row = blockIdx.x;            // b*N + i
    __shared__ float hrow[IN_DIM];
    int t = threadIdx.x;
    if (t < IN_DIM) hrow[t] = hin[(size_t)row * IN_DIM + t];
    __syncthreads();

    int side = t >> 7;
    int hd = t & 127;
    int head = hd >> 4, d = hd & 15;
    const float* W = (side ? Wr : Wl) + head * (IN_DIM * HD) + d;
    float acc = 0.f;
#pragma unroll 16
    for (int k = 0; k < IN_DIM; ++k)
        acc = fmaf(hrow[k], W[k * HD], acc);

    int b = row >> 9, i = row & (N_SZ - 1);
    float* g = side ? gr : gl;
    g[((size_t)(head * B_SZ + b) * N_SZ + i) * HD + d] = acc;
}

// ================= attn partial: block = (hb, itile(8), seg(2)) =================
// score = 0.6*(a.gl_i) + 0.6*(a.gr_j) + 0.4 * sum_d a_d*|gl_id + gr_jd|
// 64 i-rows x 256 j per block; thread = (il, jt): 32 main-loop iters.
__global__ __launch_bounds__(TPB, 4) void attn_part_kernel(
    const float* __restrict__ gl, const float* __restrict__ gr,
    const float* __restrict__ Wak, const unsigned char* __restrict__ mask,
    float* __restrict__ opart, float* __restrict__ lpart)
{
    __shared__ float grs[JB * GR_STRIDE];     // 20480 B
    __shared__ float gls[ROWS * GLS_STRIDE];  //  5120 B
    __shared__ float crs[JB];                 //  1024 B : 0.6*(a . gr_j)

    int bid = blockIdx.x;
    int seg = bid & (JSEG - 1);
    int itile = (bid >> 1) & 7;
    int hb = bid >> 4;                 // head*4 + b
    int head = hb >> 2, b = hb & 3;
    int t = threadIdx.x;
    int j0 = seg * JB;

    int il = t >> 3;                   // 0..63
    int jt = t & 7;                    // 0..7
    int i = itile * ROWS + il;

    // stage this segment's g_r rows (256 x 16 floats) via float4
    const float* grp = gr + ((size_t)hb * N_SZ + j0) * HD;
    for (int idx4 = t; idx4 < JB * HD / 4; idx4 += TPB) {
        float4 v = ((const float4*)grp)[idx4];
        int j = idx4 >> 2, dq = (idx4 & 3) * 4;
        float* p = &grs[j * GR_STRIDE + dq];
        *(v2f*)p = (v2f){v.x, v.y};
        *(v2f*)(p + 2) = (v2f){v.z, v.w};
    }
    // stage g_l for our 64 rows (1024 floats)
    const float* glp = gl + ((size_t)hb * N_SZ + itile * ROWS) * HD;
#pragma unroll
    for (int k = 0; k < 2; ++k) {
        int idx = k * TPB + t;
        gls[(idx >> 4) * GLS_STRIDE + (idx & 15)] = glp[idx];
    }

    // prefetch mask bits (32 j's per lane, strided by JT) — independent of LDS
    const unsigned char* mrow = mask + ((size_t)(b * N_SZ + i)) * N_SZ + j0;
    unsigned mbits = 0;
#pragma unroll
    for (int jj = 0; jj < JB / JT; ++jj)
        mbits |= (mrow[jj * JT + jt] ? 1u : 0u) << jj;

    __syncthreads();

    const float* ap = Wak + head * HD;   // uniform -> scalar loads

    // cr06[j] = 0.6 * (a . gr_j)
    if (t < JB) {
        const float* r = &grs[t * GR_STRIDE];
        float acc = 0.f;
#pragma unroll
        for (int dd = 0; dd < HD; ++dd) acc = fmaf(ap[dd], r[dd], acc);
        crs[t] = 0.6f * acc;
    }

    v2f glv[HD / 2], o[HD / 2];
    const float* grow = &gls[il * GLS_STRIDE];
#pragma unroll
    for (int e = 0; e < HD / 2; ++e) glv[e] = *(const v2f*)(grow + 2 * e);
    float cl06;
    {
        float acc = 0.f;
#pragma unroll
        for (int dd = 0; dd < HD; ++dd) acc = fmaf(ap[dd], grow[dd], acc);
        cl06 = 0.6f * acc;
    }
#pragma unroll
    for (int e = 0; e < HD / 2; ++e) o[e] = (v2f){0.f, 0.f};

    __syncthreads();                   // crs ready

    float l = 0.f;

#pragma unroll 2
    for (int jj = 0; jj < JB / JT; ++jj) {
        int j = jj * JT + jt;          // segment-relative
        const float* r = &grs[j * GR_STRIDE];
        float4 g01 = *(const float4*)(r);
        float4 g23 = *(const float4*)(r + 4);
        float4 g45 = *(const float4*)(r + 8);
        float4 g67 = *(const float4*)(r + 12);
        v2f gj[HD / 2] = {
            (v2f){g01.x, g01.y}, (v2f){g01.z, g01.w},
            (v2f){g23.x, g23.y}, (v2f){g23.z, g23.w},
            (v2f){g45.x, g45.y}, (v2f){g45.z, g45.w},
            (v2f){g67.x, g67.y}, (v2f){g67.z, g67.w}};

        float s0 = 0.f, s1 = 0.f;
#pragma unroll
        for (int e = 0; e < HD / 2; ++e) {       // pk_add + 2 fma (|x| free mod)
            v2f x = glv[e] + gj[e];
            s0 = fmaf(ap[2 * e],     fabsf(x.x), s0);
            s1 = fmaf(ap[2 * e + 1], fabsf(x.y), s1);
        }
        float s = fmaf(0.4f, s0 + s1, cl06 + crs[j]);
        s = fminf(s, 80.f);
        if (mbits & (1u << jj)) s = -1e30f;

        float p = __expf(s);
        l += p;
        v2f pv = (v2f){p, p};
#pragma unroll
        for (int e = 0; e < HD / 2; ++e)
            o[e] += pv * gj[e];                   // v_pk_fma_f32
    }

    // sum-merge across the 8 jt lanes (3 rounds)
#pragma unroll
    for (int off = 1; off < JT; off <<= 1) {
        l += __shfl_xor(l, off, 64);
#pragma unroll
        for (int e = 0; e < HD / 2; ++e) {
            v2f other;
            other.x = __shfl_xor(o[e].x, off, 64);
            other.y = __shfl_xor(o[e].y, off, 64);
            o[e] += other;
        }
    }

    if (jt == 0) {
        float res[HD];
#pragma unroll
        for (int e = 0; e < HD / 2; ++e) { res[2 * e] = o[e].x; res[2 * e + 1] = o[e].y; }
        float* op = opart + ((size_t)(hb * JSEG + seg) * N_SZ + i) * HD;
        *(float4*)op = *(float4*)res;
        *(float4*)(op + 4) = *(float4*)(res + 4);
        *(float4*)(op + 8) = *(float4*)(res + 8);
        *(float4*)(op + 12) = *(float4*)(res + 12);
        lpart[(size_t)(hb * JSEG + seg) * N_SZ + i] = l;
    }
}

// ================= combine: sum segments, normalize, relu =================
__global__ __launch_bounds__(256) void combine_kernel(
    const float* __restrict__ opart, const float* __restrict__ lpart,
    float* __restrict__ out)
{
    int gid = blockIdx.x * 256 + threadIdx.x;   // 0..262143
    int d = gid & 15;
    int r = gid >> 4;                           // hb*512 + i
    int i = r & (N_SZ - 1);
    int hb = r >> 9;
    int head = hb >> 2, b = hb & 3;

    float o = opart[((size_t)(hb * JSEG + 0) * N_SZ + i) * HD + d]
            + opart[((size_t)(hb * JSEG + 1) * N_SZ + i) * HD + d];
    float l = lpart[(size_t)(hb * JSEG + 0) * N_SZ + i]
            + lpart[(size_t)(hb * JSEG + 1) * N_SZ + i];
    out[((size_t)(b * N_SZ + i)) * (NH * HD) + head * HD + d] = fmaxf(o / l, 0.f);
}

// ================= fallback: fused kernel (no workspace) =================
__global__ __launch_bounds__(TPB) void gatv2_fused(
    const float* __restrict__ hin, const unsigned char* __restrict__ mask,
    const float* __restrict__ Wl, const float* __restrict__ Wr,
    const float* __restrict__ Wak, float* __restrict__ out)
{
    __shared__ float wrs[IN_DIM * HD];
    __shared__ float hsh[32][IN_DIM + 1];
    __shared__ float grs[N_SZ * 18];
    __shared__ float gls[32][HD];

    int bid = blockIdx.x;
    int itile = bid & 15;
    int hb = bid >> 4;
    int head = hb >> 2, b = hb & 3;
    int t = threadIdx.x;

    int jl = t >> 4;
    int d  = t & 15;

    for (int idx = t; idx < IN_DIM * HD; idx += TPB)
        wrs[idx] = Wr[head * IN_DIM * HD + idx];

    const float* hb_base = hin + (size_t)b * N_SZ * IN_DIM;
    const float* wlcol = Wl + head * IN_DIM * HD + d;

    for (int c = 0; c < N_SZ / 32; ++c) {
        __syncthreads();
        const float* hc = hb_base + (size_t)c * 32 * IN_DIM;
        for (int idx = t; idx < 32 * IN_DIM; idx += TPB)
            hsh[idx >> 7][idx & 127] = hc[idx];
        __syncthreads();

        float acc = 0.f;
#pragma unroll 16
        for (int k = 0; k < IN_DIM; ++k)
            acc = fmaf(hsh[jl][k], wrs[k * HD + d], acc);
        grs[(c * 32 + jl) * 18 + d] = acc;

        if (c == itile) {
            float accl = 0.f;
#pragma unroll 16
            for (int k = 0; k < IN_DIM; ++k)
                accl = fmaf(hsh[jl][k], wlcol[k * HD], accl);
            gls[jl][d] = accl;
        }
    }
    __syncthreads();

    int il = jl;
    int jt = d;
    int i = itile * 32 + il;

    float glv[HD], avv[HD];
#pragma unroll
    for (int dd = 0; dd < HD; ++dd) glv[dd] = gls[il][dd];
    const float* ap = Wak + head * HD;
#pragma unroll
    for (int dd = 0; dd < HD; ++dd) avv[dd] = ap[dd];

    const unsigned char* mrow = mask + ((size_t)(b * N_SZ + i)) * N_SZ;

    float m = -1e30f, l = 0.f;
    float o[HD];
#pragma unroll
    for (int dd = 0; dd < HD; ++dd) o[dd] = 0.f;

    for (int jj = 0; jj < N_SZ / 16; ++jj) {
        int j = jj * 16 + jt;
        const float* r = &grs[j * 18];
        float gj[HD];
#pragma unroll
        for (int e = 0; e < HD / 2; ++e) {
            float2 v = *(const float2*)(r + 2 * e);
            gj[2 * e] = v.x; gj[2 * e + 1] = v.y;
        }

        float s = 0.f;
#pragma unroll
        for (int dd = 0; dd < HD; ++dd) {
            float x = glv[dd] + gj[dd];
            float lr = fmaxf(x, SLOPE * x);
            s = fmaf(avv[dd], lr, s);
        }
        if (mrow[j]) s = -1e30f;

        float mn = fmaxf(m, s);
        float cc = __expf(m - mn);
        float p = __expf(s - mn);
        l = fmaf(l, cc, p);
#pragma unroll
        for (int dd = 0; dd < HD; ++dd)
            o[dd] = fmaf(o[dd], cc, p * gj[dd]);
        m = mn;
    }

#pragma unroll
    for (int off = 1; off < 16; off <<= 1) {
        float mo = __shfl_xor(m, off, 64);
        float lo = __shfl_xor(l, off, 64);
        float mn = fmaxf(m, mo);
        float c1 = __expf(m - mn), c2 = __expf(mo - mn);
        l = l * c1 + lo * c2;
#pragma unroll
        for (int dd = 0; dd < HD; ++dd)
            o[dd] = o[dd] * c1 + __shfl_xor(o[dd], off, 64) * c2;
        m = mn;
    }

    if (jt == 0) {
        float inv = 1.f / l;
        float res[HD];
#pragma unroll
        for (int dd = 0; dd < HD; ++dd)
            res[dd] = fmaxf(o[dd] * inv, 0.f);
        float* op = out + ((size_t)(b * N_SZ + i)) * (NH * HD) + head * HD;
#pragma unroll
        for (int e = 0; e < HD / 4; ++e)
            *(float4*)(op + 4 * e) = *(float4*)(res + 4 * e);
    }
}

extern "C" void kernel_launch(void* const* d_in, const int* in_sizes, int n_in,
                              void* d_out, int out_size, void* d_ws, size_t ws_size,
                              hipStream_t stream) {
    const float* hin = (const float*)d_in[0];
    const unsigned char* mask = (const unsigned char*)d_in[1];
    const float* Wl = (const float*)d_in[2];
    const float* Wr = (const float*)d_in[3];
    const float* Wak = (const float*)d_in[4];
    float* out = (float*)d_out;
    (void)in_sizes; (void)n_in; (void)out_size;

    const size_t need = (size_t)WS_TOT * sizeof(float);   // ~4.3 MB

    if (ws_size >= need && d_ws != nullptr) {
        float* ws = (float*)d_ws;
        float* gl = ws + WS_GL;
        float* gr = ws + WS_GR;
        float* op = ws + WS_OP;
        float* lp = ws + WS_LP;
        proj_kernel<<<B_SZ * N_SZ, 256, 0, stream>>>(hin, Wl, Wr, gl, gr);
        attn_part_kernel<<<NH * B_SZ * (N_SZ / ROWS) * JSEG, TPB, 0, stream>>>(
            gl, gr, Wak, mask, op, lp);
        combine_kernel<<<(NH * B_SZ * N_SZ * HD) / 256, 256, 0, stream>>>(
            op, lp, out);
    } else {
        gatv2_fused<<<NH * B_SZ * (N_SZ / 32), TPB, 0, stream>>>(
            hin, mask, Wl, Wr, Wak, out);
    }
}

// Round 11
// 86.518 us; speedup vs baseline: 1.7714x; 1.0968x over previous
//
#include <hip/hip_runtime.h>
#include <hip/hip_bf16.h>

#define B_SZ 4
#define N_SZ 512
#define IN_DIM 128
#define NH 8
#define HD 16
#define SLOPE 0.2f

#define ROWS 32
#define JT   16
#define TPB  512
#define GR_STRIDE 20             // 80 B rows: 16B-aligned b128; jt/jt+8 2-way alias = free
#define GLS_STRIDE 20

typedef float v2f __attribute__((ext_vector_type(2)));

// ws layout (floats): just gl, gr
#define WS_GL 0
#define WS_GR (NH * B_SZ * N_SZ * HD)                    // 262144
#define WS_TOT (2 * WS_GR)

// ---------------- proj as register-tiled GEMM ----------------
// C(2048 x 256) = h(2048 x 128) @ W(128 x 256), cols = (side, head, d).
// block: 32 rows x 64 cols, k-chunks of 64; thread (ty 0..15, tx 0..15) owns 2x4.
#define PM 32
#define PKC 64
#define AT_S 38    // At[k][r] stride (even -> b64-aligned reads; 4-way write alias)
#define BT_S 68    // Bs[k][c] stride (16B-aligned b128; 2-way alias free)

__global__ __launch_bounds__(256) void proj_gemm(
    const float* __restrict__ hin, const float* __restrict__ Wl,
    const float* __restrict__ Wr, float* __restrict__ gl, float* __restrict__ gr)
{
    __shared__ float At[PKC * AT_S];   //  9728 B : A-chunk transposed
    __shared__ float Bs[PKC * BT_S];   // 17408 B : W-chunk

    int rt = blockIdx.x >> 2;          // 0..63 row tile (32 rows)
    int ct = blockIdx.x & 3;           // 0..3  col tile (64 cols)
    int side = ct >> 1;
    int headbase = (ct & 1) * 4;
    const float* Wsrc = side ? Wr : Wl;
    int rowbase = rt * PM;

    int t = threadIdx.x;
    int ty = t >> 4;                   // rows ty*2 + {0,1}
    int tx = t & 15;                   // cols tx*4 .. tx*4+3

    float acc[2][4] = {{0.f,0.f,0.f,0.f},{0.f,0.f,0.f,0.f}};

    for (int kc = 0; kc < IN_DIM; kc += PKC) {
        __syncthreads();
        // stage A transposed: 32 rows x 16 k-quads = 512 tasks
#pragma unroll
        for (int it = 0; it < 2; ++it) {
            int task = it * 256 + t;
            int r = task >> 4, kq = task & 15;
            float4 v = *(const float4*)&hin[(size_t)(rowbase + r) * IN_DIM + kc + kq * 4];
            At[(kq * 4 + 0) * AT_S + r] = v.x;
            At[(kq * 4 + 1) * AT_S + r] = v.y;
            At[(kq * 4 + 2) * AT_S + r] = v.z;
            At[(kq * 4 + 3) * AT_S + r] = v.w;
        }
        // stage B: 64 k x 16 col-quads = 1024 tasks
#pragma unroll
        for (int it = 0; it < 4; ++it) {
            int task = it * 256 + t;
            int k = task >> 4, cc4 = task & 15;
            int head = headbase + (cc4 >> 2);
            int dq = (cc4 & 3) * 4;
            float4 v = *(const float4*)&Wsrc[head * (IN_DIM * HD) + (kc + k) * HD + dq];
            *(float4*)&Bs[k * BT_S + cc4 * 4] = v;
        }
        __syncthreads();

#pragma unroll 16
        for (int k = 0; k < PKC; ++k) {
            float2 a = *(const float2*)&At[k * AT_S + ty * 2];
            float4 b = *(const float4*)&Bs[k * BT_S + tx * 4];
            acc[0][0] = fmaf(a.x, b.x, acc[0][0]);
            acc[0][1] = fmaf(a.x, b.y, acc[0][1]);
            acc[0][2] = fmaf(a.x, b.z, acc[0][2]);
            acc[0][3] = fmaf(a.x, b.w, acc[0][3]);
            acc[1][0] = fmaf(a.y, b.x, acc[1][0]);
            acc[1][1] = fmaf(a.y, b.y, acc[1][1]);
            acc[1][2] = fmaf(a.y, b.z, acc[1][2]);
            acc[1][3] = fmaf(a.y, b.w, acc[1][3]);
        }
    }

    int head = headbase + (tx >> 2);
    int d4 = (tx & 3) * 4;
    float* g = side ? gr : gl;
#pragma unroll
    for (int r = 0; r < 2; ++r) {
        int row = rowbase + ty * 2 + r;
        int b = row >> 9, i = row & (N_SZ - 1);
        float4 v = {acc[r][0], acc[r][1], acc[r][2], acc[r][3]};
        *(float4*)&g[((size_t)(head * B_SZ + b) * N_SZ + i) * HD + d4] = v;
    }
}

// ---------------- attn: block = (hb, itile of 32 rows), full j range ----------------
// score = 0.6*(a.gl_i) + 0.6*(a.gr_j) + 0.4 * sum_d a_d*|gl_id + gr_jd|
__global__ __launch_bounds__(TPB, 4) void attn_kernel(
    const float* __restrict__ gl, const float* __restrict__ gr,
    const float* __restrict__ Wak, const unsigned char* __restrict__ mask,
    float* __restrict__ out)
{
    __shared__ float grs[N_SZ * GR_STRIDE];     // 40960 B
    __shared__ float gls[ROWS * GLS_STRIDE];    //  2560 B
    __shared__ float crs[N_SZ];                 //  2048 B

    int bid = blockIdx.x;
    int itile = bid & 15;
    int hb = bid >> 4;                 // head*4 + b
    int head = hb >> 2, b = hb & 3;
    int t = threadIdx.x;

    int il = t >> 4;                   // 0..31
    int jt = t & 15;                   // 0..15
    int i = itile * ROWS + il;

    // stage g_r (512 x 16) via float4 (grs rows 16B-aligned)
    const float* grp = gr + (size_t)hb * (N_SZ * HD);
#pragma unroll
    for (int it = 0; it < 4; ++it) {
        int idx4 = it * TPB + t;
        float4 v = ((const float4*)grp)[idx4];
        int j = idx4 >> 2, dq = (idx4 & 3) * 4;
        *(float4*)&grs[j * GR_STRIDE + dq] = v;
    }
    // stage g_l for our 32 rows
    const float* glp = gl + ((size_t)hb * N_SZ + itile * ROWS) * HD;
    {
        int row = t >> 4, d = t & 15;
        gls[row * GLS_STRIDE + d] = glp[t];
    }

    // prefetch mask bits (independent byte loads, one latency hit)
    const unsigned char* mrow = mask + ((size_t)(b * N_SZ + i)) * N_SZ;
    unsigned mbits = 0;
#pragma unroll
    for (int jj = 0; jj < N_SZ / JT; ++jj)
        mbits |= (mrow[jj * JT + jt] ? 1u : 0u) << jj;

    __syncthreads();

    const float* ap = Wak + head * HD;   // uniform -> scalar loads

    // crs[j] = 0.6 * (a . gr_j), one j per thread
    {
        const float* r = &grs[t * GR_STRIDE];
        float acc = 0.f;
#pragma unroll
        for (int dd = 0; dd < HD; ++dd) acc = fmaf(ap[dd], r[dd], acc);
        crs[t] = 0.6f * acc;
    }

    v2f glv[HD / 2], o[HD / 2];
    const float* grow = &gls[il * GLS_STRIDE];
#pragma unroll
    for (int e = 0; e < HD / 2; ++e) glv[e] = *(const v2f*)(grow + 2 * e);
    float cl06;
    {
        float acc = 0.f;
#pragma unroll
        for (int dd = 0; dd < HD; ++dd) acc = fmaf(ap[dd], grow[dd], acc);
        cl06 = 0.6f * acc;
    }
#pragma unroll
    for (int e = 0; e < HD / 2; ++e) o[e] = (v2f){0.f, 0.f};

    __syncthreads();                   // crs ready

    float l = 0.f;

#pragma unroll 2
    for (int jj = 0; jj < N_SZ / JT; ++jj) {
        int j = jj * JT + jt;
        const float* r = &grs[j * GR_STRIDE];
        float4 g01 = *(const float4*)(r);
        float4 g23 = *(const float4*)(r + 4);
        float4 g45 = *(const float4*)(r + 8);
        float4 g67 = *(const float4*)(r + 12);
        v2f gj[HD / 2] = {
            (v2f){g01.x, g01.y}, (v2f){g01.z, g01.w},
            (v2f){g23.x, g23.y}, (v2f){g23.z, g23.w},
            (v2f){g45.x, g45.y}, (v2f){g45.z, g45.w},
            (v2f){g67.x, g67.y}, (v2f){g67.z, g67.w}};

        float s0 = 0.f, s1 = 0.f;
#pragma unroll
        for (int e = 0; e < HD / 2; ++e) {       // pk_add + 2 scalar fma (|x| free mod)
            v2f x = glv[e] + gj[e];
            s0 = fmaf(ap[2 * e],     fabsf(x.x), s0);
            s1 = fmaf(ap[2 * e + 1], fabsf(x.y), s1);
        }
        float s = fmaf(0.4f, s0 + s1, cl06 + crs[j]);
        s = fminf(s, 80.f);
        if (mbits & (1u << jj)) s = -1e30f;

        float p = __expf(s);
        l += p;
        v2f pv = (v2f){p, p};
#pragma unroll
        for (int e = 0; e < HD / 2; ++e)
            o[e] += pv * gj[e];                   // v_pk_fma_f32
    }

    // sum-merge across the 16 jt lanes
#pragma unroll
    for (int off = 1; off < JT; off <<= 1) {
        l += __shfl_xor(l, off, 64);
#pragma unroll
        for (int e = 0; e < HD / 2; ++e) {
            v2f other;
            other.x = __shfl_xor(o[e].x, off, 64);
            other.y = __shfl_xor(o[e].y, off, 64);
            o[e] += other;
        }
    }

    if (jt == 0) {
        float inv = 1.f / l;
        float res[HD];
#pragma unroll
        for (int e = 0; e < HD / 2; ++e) {
            res[2 * e]     = fmaxf(o[e].x * inv, 0.f);
            res[2 * e + 1] = fmaxf(o[e].y * inv, 0.f);
        }
        float* op = out + ((size_t)(b * N_SZ + i)) * (NH * HD) + head * HD;
        *(float4*)op = *(float4*)res;
        *(float4*)(op + 4) = *(float4*)(res + 4);
        *(float4*)(op + 8) = *(float4*)(res + 8);
        *(float4*)(op + 12) = *(float4*)(res + 12);
    }
}

// ---------------- fallback: fused kernel (no workspace) ----------------
__global__ __launch_bounds__(TPB) void gatv2_fused(
    const float* __restrict__ hin, const unsigned char* __restrict__ mask,
    const float* __restrict__ Wl, const float* __restrict__ Wr,
    const float* __restrict__ Wak, float* __restrict__ out)
{
    __shared__ float wrs[IN_DIM * HD];
    __shared__ float hsh[32][IN_DIM + 1];
    __shared__ float grs[N_SZ * 18];
    __shared__ float gls[32][HD];

    int bid = blockIdx.x;
    int itile = bid & 15;
    int hb = bid >> 4;
    int head = hb >> 2, b = hb & 3;
    int t = threadIdx.x;

    int jl = t >> 4;
    int d  = t & 15;

    for (int idx = t; idx < IN_DIM * HD; idx += TPB)
        wrs[idx] = Wr[head * IN_DIM * HD + idx];

    const float* hb_base = hin + (size_t)b * N_SZ * IN_DIM;
    const float* wlcol = Wl + head * IN_DIM * HD + d;

    for (int c = 0; c < N_SZ / 32; ++c) {
        __syncthreads();
        const float* hc = hb_base + (size_t)c * 32 * IN_DIM;
        for (int idx = t; idx < 32 * IN_DIM; idx += TPB)
            hsh[idx >> 7][idx & 127] = hc[idx];
        __syncthreads();

        float acc = 0.f;
#pragma unroll 16
        for (int k = 0; k < IN_DIM; ++k)
            acc = fmaf(hsh[jl][k], wrs[k * HD + d], acc);
        grs[(c * 32 + jl) * 18 + d] = acc;

        if (c == itile) {
            float accl = 0.f;
#pragma unroll 16
            for (int k = 0; k < IN_DIM; ++k)
                accl = fmaf(hsh[jl][k], wlcol[k * HD], accl);
            gls[jl][d] = accl;
        }
    }
    __syncthreads();

    int il = jl, jt = d;
    int i = itile * 32 + il;

    float glv[HD], avv[HD];
#pragma unroll
    for (int dd = 0; dd < HD; ++dd) glv[dd] = gls[il][dd];
    const float* ap = Wak + head * HD;
#pragma unroll
    for (int dd = 0; dd < HD; ++dd) avv[dd] = ap[dd];

    const unsigned char* mrow = mask + ((size_t)(b * N_SZ + i)) * N_SZ;

    float m = -1e30f, l = 0.f;
    float o[HD];
#pragma unroll
    for (int dd = 0; dd < HD; ++dd) o[dd] = 0.f;

    for (int jj = 0; jj < N_SZ / 16; ++jj) {
        int j = jj * 16 + jt;
        const float* r = &grs[j * 18];
        float gj[HD];
#pragma unroll
        for (int e = 0; e < HD / 2; ++e) {
            float2 v = *(const float2*)(r + 2 * e);
            gj[2 * e] = v.x; gj[2 * e + 1] = v.y;
        }

        float s = 0.f;
#pragma unroll
        for (int dd = 0; dd < HD; ++dd) {
            float x = glv[dd] + gj[dd];
            float lr = fmaxf(x, SLOPE * x);
            s = fmaf(avv[dd], lr, s);
        }
        if (mrow[j]) s = -1e30f;

        float mn = fmaxf(m, s);
        float cc = __expf(m - mn);
        float p = __expf(s - mn);
        l = fmaf(l, cc, p);
#pragma unroll
        for (int dd = 0; dd < HD; ++dd)
            o[dd] = fmaf(o[dd], cc, p * gj[dd]);
        m = mn;
    }

#pragma unroll
    for (int off = 1; off < 16; off <<= 1) {
        float mo = __shfl_xor(m, off, 64);
        float lo = __shfl_xor(l, off, 64);
        float mn = fmaxf(m, mo);
        float c1 = __expf(m - mn), c2 = __expf(mo - mn);
        l = l * c1 + lo * c2;
#pragma unroll
        for (int dd = 0; dd < HD; ++dd)
            o[dd] = o[dd] * c1 + __shfl_xor(o[dd], off, 64) * c2;
        m = mn;
    }

    if (jt == 0) {
        float inv = 1.f / l;
        float res[HD];
#pragma unroll
        for (int dd = 0; dd < HD; ++dd)
            res[dd] = fmaxf(o[dd] * inv, 0.f);
        float* op = out + ((size_t)(b * N_SZ + i)) * (NH * HD) + head * HD;
#pragma unroll
        for (int e = 0; e < HD / 4; ++e)
            *(float4*)(op + 4 * e) = *(float4*)(res + 4 * e);
    }
}

extern "C" void kernel_launch(void* const* d_in, const int* in_sizes, int n_in,
                              void* d_out, int out_size, void* d_ws, size_t ws_size,
                              hipStream_t stream) {
    const float* hin = (const float*)d_in[0];
    const unsigned char* mask = (const unsigned char*)d_in[1];
    const float* Wl = (const float*)d_in[2];
    const float* Wr = (const float*)d_in[3];
    const float* Wak = (const float*)d_in[4];
    float* out = (float*)d_out;
    (void)in_sizes; (void)n_in; (void)out_size;

    const size_t need = (size_t)WS_TOT * sizeof(float);   // 2 MB

    if (ws_size >= need && d_ws != nullptr) {
        float* ws = (float*)d_ws;
        float* gl = ws + WS_GL;
        float* gr = ws + WS_GR;
        proj_gemm<<<(B_SZ * N_SZ / PM) * 4, 256, 0, stream>>>(hin, Wl, Wr, gl, gr);
        attn_kernel<<<NH * B_SZ * (N_SZ / ROWS), TPB, 0, stream>>>(
            gl, gr, Wak, mask, out);
    } else {
        gatv2_fused<<<NH * B_SZ * (N_SZ / 32), TPB, 0, stream>>>(
            hin, mask, Wl, Wr, Wak, out);
    }
}